// Round 8
// baseline (44615.070 us; speedup 1.0000x reference)
//
#include <hip/hip_runtime.h>
#include <stdint.h>

#define T_N   128
#define B_N   64
#define OBS   32
#define C_N   33      // OBS+1
#define HID   64
#define WID   128
#define FOUT  2112    // HID*C_N
#define OUTD  32
#define NSUB  4
#define NTH   1024
#define NC    4                      // chains (batch elements) per block
#define NBLK  (B_N/NC)               // 16 blocks

// d_ws: 32 planes of [NTH][8 bf16] = coalesced load-order copy of fWo rows
// r0(tid), r1(tid);  plane p = 2*j + half  (identical to round-4 layout)
#define WS_PLANES 32
#define PLB       (NTH * 16)
#define WS_NEED   ((size_t)WS_PLANES * PLB)   // 512 KB

__device__ __forceinline__ float b2f(unsigned short u) {
    return __uint_as_float(((unsigned int)u) << 16);
}
__device__ __forceinline__ float b2f_lo(unsigned int u) {
    return __uint_as_float(u << 16);
}
__device__ __forceinline__ float b2f_hi(unsigned int u) {
    return __uint_as_float(u & 0xffff0000u);
}
__device__ __forceinline__ unsigned short f2b(float f) {
    unsigned int u = __float_as_uint(f);
    unsigned int lsb = (u >> 16) & 1u;
    u += 0x7fffu + lsb;   // round to nearest even
    return (unsigned short)(u >> 16);
}
__device__ __forceinline__ unsigned int pack2(float a, float b) {
    return ((unsigned int)f2b(a)) | (((unsigned int)f2b(b)) << 16);
}
__device__ __forceinline__ float softplus_f(float x) {
    return fmaxf(x, 0.f) + __logf(1.f + __expf(-fabsf(x)));
}
__device__ __forceinline__ float tanh_fast(float x) {
    float e = __expf(2.f * x);
    return 1.f - 2.f / (e + 1.f);
}

// ---- dtype policies -------------------------------------------------------
struct PolBF16 {
    static __device__ __forceinline__ float ld(const void* p, int i) {
        return b2f(((const unsigned short*)p)[i]);
    }
    static __device__ __forceinline__ void ld8(const void* p, int i, float* o) {
        uint4 u = *(const uint4*)((const unsigned short*)p + i);
        o[0]=b2f_lo(u.x); o[1]=b2f_hi(u.x); o[2]=b2f_lo(u.y); o[3]=b2f_hi(u.y);
        o[4]=b2f_lo(u.z); o[5]=b2f_hi(u.z); o[6]=b2f_lo(u.w); o[7]=b2f_hi(u.w);
    }
    static __device__ __forceinline__ void st(void* p, int i, float v) {
        ((unsigned short*)p)[i] = f2b(v);
    }
};
struct PolF32 {
    static __device__ __forceinline__ float ld(const void* p, int i) {
        return ((const float*)p)[i];
    }
    static __device__ __forceinline__ void ld8(const void* p, int i, float* o) {
        const float4* q = (const float4*)((const float*)p + i);
        float4 a = q[0], b = q[1];
        o[0]=a.x; o[1]=a.y; o[2]=a.z; o[3]=a.w;
        o[4]=b.x; o[5]=b.y; o[6]=b.z; o[7]=b.w;
    }
    static __device__ __forceinline__ void st(void* p, int i, float v) {
        ((float*)p)[i] = v;
    }
};

// LDS: per-thread-keyed weights (16B lane stride) + NC chains of activations
struct __align__(16) Smem {
    uint4 whv[3][2][NTH];            // 96 KB : hidden weights (bf16x8 chunks)
    uint4 w0v[NTH];                  // 16 KB : layer0 weights
    uint4 wxv[NTH];                  // 16 KB : output rows c==32
    float h[2][NC][WID];             // 4 KB  : ping-pong hidden vectors
    float y[NC][HID];
    float yt[NC][HID];
    float yacc[NC][HID];             // RK4 weighted-k accumulator
    float xd[NC][C_N], d0[NC][C_N], cc[NC][C_N], bb[NC][C_N];
    float fb0[WID];
    float fbh[3][WID];
    float lWt[HID*OUTD];             // transposed [k][o]
};  // ~147 KB

// ---- weight prep: fWo -> coalesced bf16 planes in d_ws --------------------
template<class P>
__device__ __forceinline__ void prep_body(const void* fWo, unsigned short* ws) {
    const int bid = blockIdx.x;          // 0..31
    const int tid = threadIdx.x;
    const int j    = bid >> 1;
    const int half = bid & 1;
    const int row  = (tid >> 4) * C_N + (tid & 15) + (half ? 16 : 0);
    float v[8];
    P::ld8(fWo, row*WID + j*8, v);
    uint4 u;
    u.x = pack2(v[0], v[1]); u.y = pack2(v[2], v[3]);
    u.z = pack2(v[4], v[5]); u.w = pack2(v[6], v[7]);
    ((uint4*)ws)[bid*NTH + tid] = u;
}
__global__ __launch_bounds__(NTH)
void prep_kernel(const void* ts, const void* fWo, unsigned short* ws) {
    const bool isbf = (((const unsigned short*)ts)[1] == 0x3C00);
    if (isbf) prep_body<PolBF16>(fWo, ws);
    else      prep_body<PolF32>(fWo, ws);
}

// ---- main persistent kernel: NC chains per block --------------------------
template<class P, bool COAL>
__device__ void run_cde(
    const void* ts, const void* ys, const void* iW0, const void* ib0,
    const void* iWh, const void* ibh, const void* iWo, const void* ibo,
    const void* fW0, const void* fb0, const void* fWh, const void* fbh,
    const void* fWo, const void* fbo, const void* lW, const void* lb,
    const void* wWo, void* out, Smem& S)
{
    const int tid  = threadIdx.x;
    const int cb   = blockIdx.x * NC;      // first chain of this block
    const int row8 = tid >> 3;       // 0..127 : layer0/hidden row
    const int seg8 = tid & 7;        // 0..7   : K-segment
    const int rot8 = seg8 >> 1;      // bank-decorrelating traversal rotation
    const int g16  = tid >> 4;       // 0..63  : output group == h index
    const int l16  = tid & 15;       // 0..15  : lane within group
    const int r0   = g16*C_N + l16;        // output row (c = l16)
    const int r1   = r0 + 16;              // output row (c = 16+l16)
    const int rx   = g16*C_N + 32;         // shared row (c = 32)

    // ---- per-thread weight stash into LDS (once) ----
    {   // layer0: fW0 is [WID][HID]; this thread: row row8, k = seg8*8..+7
        const int kb = row8*HID + seg8*8;
        uint4 u;
        u.x = pack2(P::ld(fW0, kb+0), P::ld(fW0, kb+1));
        u.y = pack2(P::ld(fW0, kb+2), P::ld(fW0, kb+3));
        u.z = pack2(P::ld(fW0, kb+4), P::ld(fW0, kb+5));
        u.w = pack2(P::ld(fW0, kb+6), P::ld(fW0, kb+7));
        S.w0v[tid] = u;
    }
    // hidden: row row8, k-blocks in traversal order rotated by rot8
    #pragma unroll
    for (int l = 0; l < 3; ++l) {
        #pragma unroll
        for (int c = 0; c < 2; ++c) {
            const int j0 = (c*2 + 0 + rot8) & 3;
            const int j1 = (c*2 + 1 + rot8) & 3;
            const int k0 = (l*WID + row8)*WID + seg8*16 + j0*4;
            const int k1 = (l*WID + row8)*WID + seg8*16 + j1*4;
            uint4 u;
            u.x = pack2(P::ld(fWh, k0+0), P::ld(fWh, k0+1));
            u.y = pack2(P::ld(fWh, k0+2), P::ld(fWh, k0+3));
            u.z = pack2(P::ld(fWh, k1+0), P::ld(fWh, k1+1));
            u.w = pack2(P::ld(fWh, k1+2), P::ld(fWh, k1+3));
            S.whv[l][c][tid] = u;
        }
    }
    {   // shared output row (c==32): this lane's K-segment k=l16*8..+7
        const int kb = rx*WID + l16*8;
        uint4 u;
        u.x = pack2(P::ld(fWo, kb+0), P::ld(fWo, kb+1));
        u.y = pack2(P::ld(fWo, kb+2), P::ld(fWo, kb+3));
        u.z = pack2(P::ld(fWo, kb+4), P::ld(fWo, kb+5));
        u.w = pack2(P::ld(fWo, kb+6), P::ld(fWo, kb+7));
        S.wxv[tid] = u;
    }

    const float fb_r0 = P::ld(fbo, r0);
    const float fb_r1 = P::ld(fbo, r1);
    const float fb_rx = P::ld(fbo, rx);

    // ---- constants to LDS ----
    if (tid < WID)  S.fb0[tid] = P::ld(fb0, tid);
    if (tid < 3*WID) S.fbh[tid>>7][tid&127] = P::ld(fbh, tid);
    for (int i = tid; i < OUTD*HID; i += NTH) {
        int o = i >> 6, kk = i & 63;             // lW is [o][k]
        S.lWt[kk*OUTD + o] = P::ld(lW, i);
    }
    if (tid < NC*64) {
        int m = tid >> 6, c = tid & 63;
        if (c < C_N)
            S.xd[m][c] = (c == 0) ? P::ld(ts, 0)
                                  : P::ld(ys, (cb+m)*T_N*OBS + (c-1));
    }
    __syncthreads();

    // ---- initial MLP (relu hidden, identity out) -> y0, all NC chains ----
    if (tid < NC*WID) {
        int m = tid >> 7, row = tid & 127;
        float a = P::ld(ib0, row);
        for (int k2 = 0; k2 < C_N; ++k2)
            a += P::ld(iW0, row*C_N + k2) * S.xd[m][k2];
        S.h[0][m][row] = fmaxf(a, 0.f);
    }
    __syncthreads();
    int pp = 0;
    for (int l = 0; l < 3; ++l) {
        if (tid < NC*WID) {
            int m = tid >> 7, row = tid & 127;
            float a = P::ld(ibh, l*WID + row);
            for (int k2 = 0; k2 < WID; ++k2)
                a += P::ld(iWh, (l*WID + row)*WID + k2) * S.h[pp][m][k2];
            S.h[1-pp][m][row] = fmaxf(a, 0.f);
        }
        __syncthreads();
        pp ^= 1;
    }
    if (tid < NC*HID) {
        int m = tid >> 6, kk = tid & 63;
        float a = P::ld(ibo, kk);
        for (int k2 = 0; k2 < WID; ++k2)
            a += P::ld(iWo, kk*WID + k2) * S.h[pp][m][k2];
        S.y[m][kk] = a;
    }
    __syncthreads();
    if (tid < NC*OUTD) {
        int m = tid >> 5, o = tid & 31;
        float a = P::ld(lb, o);
        for (int k2 = 0; k2 < HID; ++k2) a += S.lWt[k2*OUTD + o] * S.y[m][k2];
        P::st(out, (cb+m)*T_N*OUTD + o, a);
    }

    // ---- sequential intervals ----
    #pragma unroll 1
    for (int iv = 0; iv < T_N-1; ++iv) {
        float t0 = P::ld(ts, iv), t1 = P::ld(ts, iv+1);
        float dt = t1 - t0;
        float hs = dt * (1.f/NSUB);
        if (tid < NC*64) {
            int m = tid >> 6, c = tid & 63;
            if (c < C_N) {
                const int ybase = (cb+m)*T_N*OBS;
                float v0 = (c==0) ? t0 : P::ld(ys, ybase + iv*OBS + (c-1));
                float v1 = (c==0) ? t1 : P::ld(ys, ybase + (iv+1)*OBS + (c-1));
                float di = (v1 - v0) / dt;
                float d0v;
                if (iv == 0) d0v = di;
                else {
                    float tm = P::ld(ts, iv-1);
                    float vm = (c==0) ? tm : P::ld(ys, ybase + (iv-1)*OBS + (c-1));
                    d0v = (v0 - vm) / (t0 - tm);
                }
                float d1v = di;
                S.d0[m][c] = d0v;
                S.cc[m][c] = (3.f*di - 2.f*d0v - d1v) / dt;
                S.bb[m][c] = (d0v + d1v - 2.f*di) / (dt*dt);
            }
        }
        __syncthreads();

        #pragma unroll 1
        for (int sub = 0; sub < NSUB; ++sub) {
            float s0 = sub * hs;
            #pragma unroll 1
            for (int st = 0; st < 4; ++st) {
                float s = (st==0) ? s0 : ((st==3) ? s0+hs : s0 + 0.5f*hs);
                const float* yb0 = (st==0) ? &S.y[0][0] : &S.yt[0][0];

                // xdot(s) for all chains (overlapped with layer0)
                if (tid < NC*64) {
                    int m = tid >> 6, c = tid & 63;
                    if (c < C_N)
                        S.xd[m][c] = S.d0[m][c]
                                   + (2.f*S.cc[m][c] + 3.f*S.bb[m][c]*s)*s;
                }

                // ---- layer 0: weights unpacked once, 4 chains ----
                {
                    uint4 w = S.w0v[tid];
                    float w0=b2f_lo(w.x), w1=b2f_hi(w.x), w2=b2f_lo(w.y),
                          w3=b2f_hi(w.y), w4=b2f_lo(w.z), w5=b2f_hi(w.z),
                          w6=b2f_lo(w.w), w7=b2f_hi(w.w);
                    float am[NC];
                    #pragma unroll
                    for (int m = 0; m < NC; ++m) {
                        const float4* y4 = (const float4*)(yb0 + m*HID + seg8*8);
                        float4 ya = y4[0], yv = y4[1];
                        am[m] = w0*ya.x + w1*ya.y + w2*ya.z + w3*ya.w
                              + w4*yv.x + w5*yv.y + w6*yv.z + w7*yv.w;
                    }
                    #pragma unroll
                    for (int m = 0; m < NC; ++m) {
                        am[m] += __shfl_xor(am[m], 1);
                        am[m] += __shfl_xor(am[m], 2);
                        am[m] += __shfl_xor(am[m], 4);
                    }
                    if (seg8 == 0) {
                        float bias = S.fb0[row8];
                        #pragma unroll
                        for (int m = 0; m < NC; ++m)
                            S.h[0][m][row8] = softplus_f(am[m] + bias);
                    }
                }
                __syncthreads();                                   // B1

                // ---- 3 hidden layers: weights unpacked once, 4 chains ----
                #pragma unroll
                for (int l = 0; l < 3; ++l) {
                    uint4 wa = S.whv[l][0][tid];
                    uint4 wb = S.whv[l][1][tid];
                    float wv0=b2f_lo(wa.x), wv1=b2f_hi(wa.x), wv2=b2f_lo(wa.y),
                          wv3=b2f_hi(wa.y), wv4=b2f_lo(wa.z), wv5=b2f_hi(wa.z),
                          wv6=b2f_lo(wa.w), wv7=b2f_hi(wa.w), wv8=b2f_lo(wb.x),
                          wv9=b2f_hi(wb.x), wv10=b2f_lo(wb.y), wv11=b2f_hi(wb.y),
                          wv12=b2f_lo(wb.z), wv13=b2f_hi(wb.z), wv14=b2f_lo(wb.w),
                          wv15=b2f_hi(wb.w);
                    float am[NC];
                    #pragma unroll
                    for (int m = 0; m < NC; ++m) {
                        const float* hb = &S.h[l & 1][m][seg8*16];
                        float a;
                        { int j=(0+rot8)&3; float4 hv=*(const float4*)(hb+j*4);
                          a  = wv0*hv.x + wv1*hv.y + wv2*hv.z + wv3*hv.w; }
                        { int j=(1+rot8)&3; float4 hv=*(const float4*)(hb+j*4);
                          a += wv4*hv.x + wv5*hv.y + wv6*hv.z + wv7*hv.w; }
                        { int j=(2+rot8)&3; float4 hv=*(const float4*)(hb+j*4);
                          a += wv8*hv.x + wv9*hv.y + wv10*hv.z + wv11*hv.w; }
                        { int j=(3+rot8)&3; float4 hv=*(const float4*)(hb+j*4);
                          a += wv12*hv.x + wv13*hv.y + wv14*hv.z + wv15*hv.w; }
                        am[m] = a;
                    }
                    #pragma unroll
                    for (int m = 0; m < NC; ++m) {
                        am[m] += __shfl_xor(am[m], 1);
                        am[m] += __shfl_xor(am[m], 2);
                        am[m] += __shfl_xor(am[m], 4);
                    }
                    if (seg8 == 0) {
                        float bias = S.fbh[l][row8];
                        #pragma unroll
                        for (int m = 0; m < NC; ++m)
                            S.h[1-(l&1)][m][row8] = softplus_f(am[m] + bias);
                    }
                    __syncthreads();                               // B2..B4
                }

                // ---- output layer (stream amortized over NC chains) ----
                {
                    float a0[NC] = {0.f,0.f,0.f,0.f};
                    float a1[NC] = {0.f,0.f,0.f,0.f};
                    float ax[NC];
                    {
                        uint4 wxu = S.wxv[tid];
                        float x0=b2f_lo(wxu.x), x1=b2f_hi(wxu.x), x2=b2f_lo(wxu.y),
                              x3=b2f_hi(wxu.y), x4=b2f_lo(wxu.z), x5=b2f_hi(wxu.z),
                              x6=b2f_lo(wxu.w), x7=b2f_hi(wxu.w);
                        #pragma unroll
                        for (int m = 0; m < NC; ++m) {
                            const float4* h4 = (const float4*)(&S.h[1][m][l16*8]);
                            float4 ha = h4[0], hb2 = h4[1];
                            ax[m] = x0*ha.x + x1*ha.y + x2*ha.z + x3*ha.w
                                  + x4*hb2.x + x5*hb2.y + x6*hb2.z + x7*hb2.w;
                        }
                    }
                    if constexpr (COAL) {
                        const uint4* wp = (const uint4*)wWo + tid;
                        #pragma unroll 2
                        for (int j = 0; j < 16; ++j) {
                            uint4 u0 = wp[(2*j+0)*NTH];
                            uint4 u1 = wp[(2*j+1)*NTH];
                            float p0=b2f_lo(u0.x), p1=b2f_hi(u0.x), p2=b2f_lo(u0.y),
                                  p3=b2f_hi(u0.y), p4=b2f_lo(u0.z), p5=b2f_hi(u0.z),
                                  p6=b2f_lo(u0.w), p7=b2f_hi(u0.w);
                            float q0=b2f_lo(u1.x), q1=b2f_hi(u1.x), q2=b2f_lo(u1.y),
                                  q3=b2f_hi(u1.y), q4=b2f_lo(u1.z), q5=b2f_hi(u1.z),
                                  q6=b2f_lo(u1.w), q7=b2f_hi(u1.w);
                            #pragma unroll
                            for (int m = 0; m < NC; ++m) {
                                const float4* h4 = (const float4*)(&S.h[1][m][j*8]);
                                float4 ha = h4[0], hb2 = h4[1];
                                a0[m] += p0*ha.x + p1*ha.y + p2*ha.z + p3*ha.w
                                       + p4*hb2.x + p5*hb2.y + p6*hb2.z + p7*hb2.w;
                                a1[m] += q0*ha.x + q1*ha.y + q2*ha.z + q3*ha.w
                                       + q4*hb2.x + q5*hb2.y + q6*hb2.z + q7*hb2.w;
                            }
                        }
                    } else {
                        #pragma unroll 2
                        for (int j = 0; j < 16; ++j) {
                            float w8[8];
                            P::ld8(fWo, r0*WID + j*8, w8);
                            #pragma unroll
                            for (int m = 0; m < NC; ++m) {
                                const float4* h4 = (const float4*)(&S.h[1][m][j*8]);
                                float4 ha = h4[0], hb2 = h4[1];
                                a0[m] += w8[0]*ha.x + w8[1]*ha.y + w8[2]*ha.z + w8[3]*ha.w
                                       + w8[4]*hb2.x + w8[5]*hb2.y + w8[6]*hb2.z + w8[7]*hb2.w;
                            }
                            P::ld8(fWo, r1*WID + j*8, w8);
                            #pragma unroll
                            for (int m = 0; m < NC; ++m) {
                                const float4* h4 = (const float4*)(&S.h[1][m][j*8]);
                                float4 ha = h4[0], hb2 = h4[1];
                                a1[m] += w8[0]*ha.x + w8[1]*ha.y + w8[2]*ha.z + w8[3]*ha.w
                                       + w8[4]*hb2.x + w8[5]*hb2.y + w8[6]*hb2.z + w8[7]*hb2.w;
                            }
                        }
                    }

                    // per-chain reductions + RK advance
                    float ks[NC];
                    #pragma unroll
                    for (int m = 0; m < NC; ++m) {
                        float axm = ax[m];
                        axm += __shfl_xor(axm, 1);
                        axm += __shfl_xor(axm, 2);
                        axm += __shfl_xor(axm, 4);
                        axm += __shfl_xor(axm, 8);      // full K-sum of row rx
                        float v0 = tanh_fast(a0[m] + fb_r0) * S.xd[m][l16];
                        float v1 = tanh_fast(a1[m] + fb_r1) * S.xd[m][16 + l16];
                        float t2 = v0 + v1;
                        t2 += __shfl_xor(t2, 1);
                        t2 += __shfl_xor(t2, 2);
                        t2 += __shfl_xor(t2, 4);
                        t2 += __shfl_xor(t2, 8);        // sum over 32 rows
                        ks[m] = t2 + tanh_fast(axm + fb_rx) * S.xd[m][32];
                    }
                    if (l16 == 0) {
                        #pragma unroll
                        for (int m = 0; m < NC; ++m) {
                            float ksum = ks[m];
                            float yg = S.y[m][g16];
                            if (st == 0) {
                                S.yacc[m][g16] = ksum;
                                S.yt[m][g16] = yg + 0.5f*hs*ksum;
                            } else if (st == 1) {
                                S.yacc[m][g16] += 2.f*ksum;
                                S.yt[m][g16] = yg + 0.5f*hs*ksum;
                            } else if (st == 2) {
                                S.yacc[m][g16] += 2.f*ksum;
                                S.yt[m][g16] = yg + hs*ksum;
                            } else {
                                S.y[m][g16] = yg
                                    + hs*(1.f/6.f)*(S.yacc[m][g16] + ksum);
                            }
                        }
                    }
                }
                __syncthreads();                                   // B5
            }
        }

        if (tid < NC*OUTD) {
            int m = tid >> 5, o = tid & 31;
            float a = P::ld(lb, o);
            #pragma unroll 8
            for (int k2 = 0; k2 < HID; ++k2) a += S.lWt[k2*OUTD + o] * S.y[m][k2];
            P::st(out, (cb+m)*T_N*OUTD + (iv+1)*OUTD + o, a);
        }
    }
}

__global__ __launch_bounds__(NTH)
void cde_kernel(const void* ts, const void* ys, const void* iW0, const void* ib0,
                const void* iWh, const void* ibh, const void* iWo, const void* ibo,
                const void* fW0, const void* fb0, const void* fWh, const void* fbh,
                const void* fWo, const void* fbo, const void* lW, const void* lb,
                const unsigned short* ws, int use_ws, void* out)
{
    __shared__ Smem S;
    const bool isbf = (((const unsigned short*)ts)[1] == 0x3C00);
    if (use_ws) {
        if (isbf)
            run_cde<PolBF16, true>(ts, ys, iW0, ib0, iWh, ibh, iWo, ibo,
                                   fW0, fb0, fWh, fbh, fWo, fbo, lW, lb,
                                   ws, out, S);
        else
            run_cde<PolF32, true>(ts, ys, iW0, ib0, iWh, ibh, iWo, ibo,
                                  fW0, fb0, fWh, fbh, fWo, fbo, lW, lb,
                                  ws, out, S);
    } else {
        if (isbf)
            run_cde<PolBF16, false>(ts, ys, iW0, ib0, iWh, ibh, iWo, ibo,
                                    fW0, fb0, fWh, fbh, fWo, fbo, lW, lb,
                                    fWo, out, S);
        else
            run_cde<PolF32, false>(ts, ys, iW0, ib0, iWh, ibh, iWo, ibo,
                                   fW0, fb0, fWh, fbh, fWo, fbo, lW, lb,
                                   fWo, out, S);
    }
}

extern "C" void kernel_launch(void* const* d_in, const int* in_sizes, int n_in,
                              void* d_out, int out_size, void* d_ws, size_t ws_size,
                              hipStream_t stream) {
    (void)in_sizes; (void)n_in; (void)out_size;
    const int use_ws = (ws_size >= WS_NEED) ? 1 : 0;
    if (use_ws) {
        hipLaunchKernelGGL(prep_kernel, dim3(WS_PLANES), dim3(NTH), 0, stream,
                           d_in[0], d_in[12], (unsigned short*)d_ws);
    }
    hipLaunchKernelGGL(cde_kernel, dim3(NBLK), dim3(NTH), 0, stream,
                       d_in[0], d_in[1], d_in[2], d_in[3], d_in[4], d_in[5],
                       d_in[6], d_in[7], d_in[8], d_in[9], d_in[10], d_in[11],
                       d_in[12], d_in[13], d_in[14], d_in[15],
                       (const unsigned short*)d_ws, use_ws, d_out);
}

// Round 9
// 13929.489 us; speedup vs baseline: 3.2029x; 3.2029x over previous
//
#include <hip/hip_runtime.h>
#include <stdint.h>

#define T_N   128
#define B_N   64
#define OBS   32
#define C_N   33      // OBS+1
#define HID   64
#define WID   128
#define FOUT  2112    // HID*C_N
#define OUTD  32
#define NSUB  4
#define NTH   1024

// d_ws: MFMA A-fragment planes for fWo.
// plane p = t*4+kb (t=tile of 16 rows, kb=K-block of 32), 64 lanes x 16B:
//   lane holds W[16t+(lane&15)][kb*32+(lane>>4)*8 + j], j=0..7 (bf16 pairs)
#define NTILE_T  132                   // 2112/16
#define NPLANES  (NTILE_T*4)           // 528
#define WS_NEED  ((size_t)NPLANES * 64 * 16)   // 540672 B

typedef __attribute__((ext_vector_type(8))) short  bf16x8;
typedef __attribute__((ext_vector_type(4))) float  f32x4;

__device__ __forceinline__ float b2f(unsigned short u) {
    return __uint_as_float(((unsigned int)u) << 16);
}
__device__ __forceinline__ float b2f_lo(unsigned int u) {
    return __uint_as_float(u << 16);
}
__device__ __forceinline__ float b2f_hi(unsigned int u) {
    return __uint_as_float(u & 0xffff0000u);
}
__device__ __forceinline__ unsigned short f2b(float f) {
    unsigned int u = __float_as_uint(f);
    unsigned int lsb = (u >> 16) & 1u;
    u += 0x7fffu + lsb;   // round to nearest even
    return (unsigned short)(u >> 16);
}
__device__ __forceinline__ unsigned int pack2(float a, float b) {
    return ((unsigned int)f2b(a)) | (((unsigned int)f2b(b)) << 16);
}
// packed truncation-hi of two f32 (exact upper bf16 halves)
__device__ __forceinline__ unsigned int pkhi(float a, float b) {
    return (__float_as_uint(a) >> 16) | (__float_as_uint(b) & 0xffff0000u);
}
// packed bf16(residual) of two f32
__device__ __forceinline__ unsigned int pklo(float a, float b) {
    float la = a - __uint_as_float(__float_as_uint(a) & 0xffff0000u);
    float lb = b - __uint_as_float(__float_as_uint(b) & 0xffff0000u);
    return pack2(la, lb);
}
__device__ __forceinline__ bf16x8 u4b8(uint4 u) {
    union { uint4 a; bf16x8 b; } x; x.a = u; return x.b;
}
__device__ __forceinline__ float softplus_f(float x) {
    return fmaxf(x, 0.f) + __logf(1.f + __expf(-fabsf(x)));
}
__device__ __forceinline__ float tanh_fast(float x) {
    float e = __expf(2.f * x);
    return 1.f - 2.f / (e + 1.f);
}

// ---- dtype policies -------------------------------------------------------
struct PolBF16 {
    static __device__ __forceinline__ float ld(const void* p, int i) {
        return b2f(((const unsigned short*)p)[i]);
    }
    static __device__ __forceinline__ void ld8(const void* p, int i, float* o) {
        uint4 u = *(const uint4*)((const unsigned short*)p + i);
        o[0]=b2f_lo(u.x); o[1]=b2f_hi(u.x); o[2]=b2f_lo(u.y); o[3]=b2f_hi(u.y);
        o[4]=b2f_lo(u.z); o[5]=b2f_hi(u.z); o[6]=b2f_lo(u.w); o[7]=b2f_hi(u.w);
    }
    static __device__ __forceinline__ void st(void* p, int i, float v) {
        ((unsigned short*)p)[i] = f2b(v);
    }
};
struct PolF32 {
    static __device__ __forceinline__ float ld(const void* p, int i) {
        return ((const float*)p)[i];
    }
    static __device__ __forceinline__ void ld8(const void* p, int i, float* o) {
        const float4* q = (const float4*)((const float*)p + i);
        float4 a = q[0], b = q[1];
        o[0]=a.x; o[1]=a.y; o[2]=a.z; o[3]=a.w;
        o[4]=b.x; o[5]=b.y; o[6]=b.z; o[7]=b.w;
    }
    static __device__ __forceinline__ void st(void* p, int i, float v) {
        ((float*)p)[i] = v;
    }
};

struct __align__(16) Smem {
    uint4 whv[3][2][NTH];            // 96 KB : hidden weights (bf16x8 chunks)
    uint4 w0v[NTH];                  // 16 KB : layer0 weights
    float rowp[2][FOUT];             // 16.5 KB : output partial dots (K halves)
    float h[2][WID];                 // ping-pong hidden vector
    float y[HID];
    float yt[HID];
    float xd[C_N], d0[C_N], cc[C_N], bb[C_N];
    float fb0[WID];
    float fbh[3][WID];
    float lWt[HID*OUTD];             // transposed [k][o]
};  // ~142 KB

// ---- weight prep: fWo -> MFMA A-fragment planes in d_ws -------------------
template<class P>
__device__ __forceinline__ void prep_body(const void* fWo, unsigned short* ws) {
    const int e    = blockIdx.x * NTH + threadIdx.x;   // 0..33791
    const int p    = e >> 6;                           // plane 0..527
    const int lane = e & 63;
    const int t    = p >> 2;
    const int kb   = p & 3;
    const int row  = 16*t + (lane & 15);
    const int k0   = kb*32 + ((lane >> 4) << 3);
    float v[8];
    P::ld8(fWo, row*WID + k0, v);
    uint4 u;
    u.x = pack2(v[0],v[1]); u.y = pack2(v[2],v[3]);
    u.z = pack2(v[4],v[5]); u.w = pack2(v[6],v[7]);
    ((uint4*)ws)[e] = u;
}
__global__ __launch_bounds__(NTH)
void prep_kernel(const void* ts, const void* fWo, unsigned short* ws) {
    const bool isbf = (((const unsigned short*)ts)[1] == 0x3C00);
    if (isbf) prep_body<PolBF16>(fWo, ws);
    else      prep_body<PolF32>(fWo, ws);
}

// ---- main persistent-per-batch kernel -------------------------------------
template<class P, bool COAL>
__device__ void run_cde(
    const void* ts, const void* ys, const void* iW0, const void* ib0,
    const void* iWh, const void* ibh, const void* iWo, const void* ibo,
    const void* fW0, const void* fb0, const void* fWh, const void* fbh,
    const void* fWo, const void* fbo, const void* lW, const void* lb,
    const void* wWo, void* out, Smem& S)
{
    const int tid  = threadIdx.x;
    const int b    = blockIdx.x;
    const int row8 = tid >> 3;       // 0..127 : layer0/hidden row
    const int seg8 = tid & 7;        // 0..7   : K-segment
    const int rot8 = seg8 >> 1;      // bank-decorrelating traversal rotation
    const int g16  = tid >> 4;       // 0..63  : output group == h index
    const int l16  = tid & 15;       // 0..15  : lane within group
    const int r0   = g16*C_N + l16;        // output row (c = l16)
    const int r1   = r0 + 16;              // output row (c = 16+l16)
    const int rx   = g16*C_N + 32;         // shared row (c = 32)
    // MFMA wave geometry
    const int wv   = tid >> 6;       // wave 0..15
    const int lane = tid & 63;
    const int pr   = wv & 7;         // tile-residue class (tiles t = pr+8i)
    const int role = wv >> 3;        // 0: k<64, 1: k>=64
    const int lg   = lane >> 4;      // 0..3

    // ---- per-thread weight stash into LDS (once) ----
    {   // layer0: fW0 is [WID][HID]; this thread: row row8, k = seg8*8..+7
        const int kb = row8*HID + seg8*8;
        uint4 u;
        u.x = pack2(P::ld(fW0, kb+0), P::ld(fW0, kb+1));
        u.y = pack2(P::ld(fW0, kb+2), P::ld(fW0, kb+3));
        u.z = pack2(P::ld(fW0, kb+4), P::ld(fW0, kb+5));
        u.w = pack2(P::ld(fW0, kb+6), P::ld(fW0, kb+7));
        S.w0v[tid] = u;
    }
    // hidden: row row8, k-blocks in traversal order rotated by rot8
    #pragma unroll
    for (int l = 0; l < 3; ++l) {
        #pragma unroll
        for (int c = 0; c < 2; ++c) {
            const int j0 = (c*2 + 0 + rot8) & 3;
            const int j1 = (c*2 + 1 + rot8) & 3;
            const int k0 = (l*WID + row8)*WID + seg8*16 + j0*4;
            const int k1 = (l*WID + row8)*WID + seg8*16 + j1*4;
            uint4 u;
            u.x = pack2(P::ld(fWh, k0+0), P::ld(fWh, k0+1));
            u.y = pack2(P::ld(fWh, k0+2), P::ld(fWh, k0+3));
            u.z = pack2(P::ld(fWh, k1+0), P::ld(fWh, k1+1));
            u.w = pack2(P::ld(fWh, k1+2), P::ld(fWh, k1+3));
            S.whv[l][c][tid] = u;
        }
    }

    const float fb_r0 = P::ld(fbo, r0);
    const float fb_r1 = P::ld(fbo, r1);
    const float fb_rx = P::ld(fbo, rx);

    // ---- constants to LDS ----
    if (tid < WID)  S.fb0[tid] = P::ld(fb0, tid);
    if (tid < 3*WID) S.fbh[tid>>7][tid&127] = P::ld(fbh, tid);
    for (int i = tid; i < OUTD*HID; i += NTH) {
        int o = i >> 6, kk = i & 63;             // lW is [o][k]
        S.lWt[kk*OUTD + o] = P::ld(lW, i);
    }
    if (tid < C_N)
        S.xd[tid] = (tid == 0) ? P::ld(ts, 0) : P::ld(ys, b*T_N*OBS + (tid-1));
    __syncthreads();

    // ---- initial MLP (relu hidden, identity out) -> y0 (runs once) ----
    if (tid < WID) {
        float a = P::ld(ib0, tid);
        for (int k2 = 0; k2 < C_N; ++k2) a += P::ld(iW0, tid*C_N + k2) * S.xd[k2];
        S.h[0][tid] = fmaxf(a, 0.f);
    }
    __syncthreads();
    int pp = 0;
    for (int l = 0; l < 3; ++l) {
        if (tid < WID) {
            float a = P::ld(ibh, l*WID + tid);
            for (int k2 = 0; k2 < WID; ++k2)
                a += P::ld(iWh, (l*WID + tid)*WID + k2) * S.h[pp][k2];
            S.h[1-pp][tid] = fmaxf(a, 0.f);
        }
        __syncthreads();
        pp ^= 1;
    }
    if (tid < HID) {
        float a = P::ld(ibo, tid);
        for (int k2 = 0; k2 < WID; ++k2)
            a += P::ld(iWo, tid*WID + k2) * S.h[pp][k2];
        S.y[tid] = a;
    }
    __syncthreads();
    if (tid < OUTD) {
        float a = P::ld(lb, tid);
        for (int k2 = 0; k2 < HID; ++k2) a += S.lWt[k2*OUTD + tid] * S.y[k2];
        P::st(out, b*T_N*OUTD + tid, a);
    }

    // ---- sequential intervals ----
    #pragma unroll 1
    for (int iv = 0; iv < T_N-1; ++iv) {
        float t0 = P::ld(ts, iv), t1 = P::ld(ts, iv+1);
        float dt = t1 - t0;
        float hs = dt * (1.f/NSUB);
        if (tid < C_N) {
            float v0 = (tid==0) ? t0 : P::ld(ys, b*T_N*OBS + iv*OBS + (tid-1));
            float v1 = (tid==0) ? t1 : P::ld(ys, b*T_N*OBS + (iv+1)*OBS + (tid-1));
            float di = (v1 - v0) / dt;
            float d0v;
            if (iv == 0) d0v = di;
            else {
                float tm = P::ld(ts, iv-1);
                float vm = (tid==0) ? tm : P::ld(ys, b*T_N*OBS + (iv-1)*OBS + (tid-1));
                d0v = (v0 - vm) / (t0 - tm);
            }
            float d1v = di;
            S.d0[tid] = d0v;
            S.cc[tid] = (3.f*di - 2.f*d0v - d1v) / dt;
            S.bb[tid] = (d0v + d1v - 2.f*di) / (dt*dt);
        }
        __syncthreads();

        #pragma unroll 1
        for (int sub = 0; sub < NSUB; ++sub) {
            float s0 = sub * hs;
            float ka = 0.f, kb = 0.f, kc = 0.f;      // RK stage sums (l16==0)
            #pragma unroll 1
            for (int st = 0; st < 4; ++st) {
                float s = (st==0) ? s0 : ((st==3) ? s0+hs : s0 + 0.5f*hs);
                const float* yin = (st==0) ? S.y : S.yt;

                // xdot(s) (threads 0..32, overlapped with layer0)
                if (tid < C_N)
                    S.xd[tid] = S.d0[tid] + (2.f*S.cc[tid] + 3.f*S.bb[tid]*s)*s;

                // ---- layer 0: 128 rows x 8 K-segs of 8, weights in LDS ----
                {
                    const float4* y4 = (const float4*)(yin + seg8*8);
                    float4 ya = y4[0], yb = y4[1];
                    uint4 w = S.w0v[tid];
                    float a = b2f_lo(w.x)*ya.x + b2f_hi(w.x)*ya.y
                            + b2f_lo(w.y)*ya.z + b2f_hi(w.y)*ya.w
                            + b2f_lo(w.z)*yb.x + b2f_hi(w.z)*yb.y
                            + b2f_lo(w.w)*yb.z + b2f_hi(w.w)*yb.w;
                    a += __shfl_xor(a, 1);
                    a += __shfl_xor(a, 2);
                    a += __shfl_xor(a, 4);
                    if (seg8 == 0) S.h[0][row8] = softplus_f(a + S.fb0[row8]);
                }
                __syncthreads();                                   // B1

                // ---- 3 hidden layers: weights from LDS (b128), shuffle ----
                #pragma unroll
                for (int l = 0; l < 3; ++l) {
                    const int hp = l & 1;
                    const float* hb = S.h[hp] + seg8*16;
                    uint4 wa = S.whv[l][0][tid];
                    uint4 wb = S.whv[l][1][tid];
                    float a;
                    { int j=(0+rot8)&3; float4 hv=*(const float4*)(hb+j*4);
                      a  = b2f_lo(wa.x)*hv.x + b2f_hi(wa.x)*hv.y
                         + b2f_lo(wa.y)*hv.z + b2f_hi(wa.y)*hv.w; }
                    { int j=(1+rot8)&3; float4 hv=*(const float4*)(hb+j*4);
                      a += b2f_lo(wa.z)*hv.x + b2f_hi(wa.z)*hv.y
                         + b2f_lo(wa.w)*hv.z + b2f_hi(wa.w)*hv.w; }
                    { int j=(2+rot8)&3; float4 hv=*(const float4*)(hb+j*4);
                      a += b2f_lo(wb.x)*hv.x + b2f_hi(wb.x)*hv.y
                         + b2f_lo(wb.y)*hv.z + b2f_hi(wb.y)*hv.w; }
                    { int j=(3+rot8)&3; float4 hv=*(const float4*)(hb+j*4);
                      a += b2f_lo(wb.z)*hv.x + b2f_hi(wb.z)*hv.y
                         + b2f_lo(wb.w)*hv.z + b2f_hi(wb.w)*hv.w; }
                    a += __shfl_xor(a, 1);
                    a += __shfl_xor(a, 2);
                    a += __shfl_xor(a, 4);
                    if (seg8 == 0) S.h[1-hp][row8] = softplus_f(a + S.fbh[l][row8]);
                    __syncthreads();                               // B2..B4
                }

                // ---- output layer ----
                const float* hin = S.h[1];              // after 3 layers
                if constexpr (COAL) {
                    // B-fragments: h split hi/lo bf16, this wave's K-half.
                    // lane covers k = role*64 + kb2*32 + lg*8 + j  (j=0..7)
                    const int kbse = role*64 + lg*8;
                    float4 p0 = *(const float4*)(hin + kbse);
                    float4 p1 = *(const float4*)(hin + kbse + 4);
                    float4 p2 = *(const float4*)(hin + kbse + 32);
                    float4 p3 = *(const float4*)(hin + kbse + 36);
                    uint4 bh0, bl0, bh1, bl1;
                    bh0.x=pkhi(p0.x,p0.y); bh0.y=pkhi(p0.z,p0.w);
                    bh0.z=pkhi(p1.x,p1.y); bh0.w=pkhi(p1.z,p1.w);
                    bl0.x=pklo(p0.x,p0.y); bl0.y=pklo(p0.z,p0.w);
                    bl0.z=pklo(p1.x,p1.y); bl0.w=pklo(p1.z,p1.w);
                    bh1.x=pkhi(p2.x,p2.y); bh1.y=pkhi(p2.z,p2.w);
                    bh1.z=pkhi(p3.x,p3.y); bh1.w=pkhi(p3.z,p3.w);
                    bl1.x=pklo(p2.x,p2.y); bl1.y=pklo(p2.z,p2.w);
                    bl1.z=pklo(p3.x,p3.y); bl1.w=pklo(p3.z,p3.w);
                    bf16x8 vh0=u4b8(bh0), vl0=u4b8(bl0);
                    bf16x8 vh1=u4b8(bh1), vl1=u4b8(bl1);

                    // stream A-fragments, 1-tile prefetch, 4 MFMA per tile
                    const uint4* ap = (const uint4*)wWo
                                    + (pr*4 + 2*role)*64 + lane;
                    const int ntile = (pr < 4) ? 17 : 16;
                    uint4 a0 = ap[0], a1 = ap[64];
                    int t = pr;
                    #pragma unroll 1
                    for (int i = 0; i < ntile; ++i) {
                        uint4 c0 = a0, c1 = a1;
                        if (i + 1 < ntile) {
                            ap += 8*4*64;               // next tile (t+8)
                            a0 = ap[0]; a1 = ap[64];
                        }
                        f32x4 acc = {0.f, 0.f, 0.f, 0.f};
                        acc = __builtin_amdgcn_mfma_f32_16x16x32_bf16(
                                  u4b8(c0), vh0, acc, 0, 0, 0);
                        acc = __builtin_amdgcn_mfma_f32_16x16x32_bf16(
                                  u4b8(c0), vl0, acc, 0, 0, 0);
                        acc = __builtin_amdgcn_mfma_f32_16x16x32_bf16(
                                  u4b8(c1), vh1, acc, 0, 0, 0);
                        acc = __builtin_amdgcn_mfma_f32_16x16x32_bf16(
                                  u4b8(c1), vl1, acc, 0, 0, 0);
                        if ((lane & 15) == 0) {         // col 0 = W.h
                            float4 st4;
                            st4.x = acc[0]; st4.y = acc[1];
                            st4.z = acc[2]; st4.w = acc[3];
                            *(float4*)&S.rowp[role][16*t + lg*4] = st4;
                        }
                        t += 8;
                    }
                    __syncthreads();                               // B5

                    // reduce + RK advance (round-4 l16-group pattern)
                    {
                        float d0v = S.rowp[0][r0] + S.rowp[1][r0];
                        float d1v = S.rowp[0][r1] + S.rowp[1][r1];
                        float dxv = S.rowp[0][rx] + S.rowp[1][rx];
                        float v0 = tanh_fast(d0v + fb_r0) * S.xd[l16];
                        float v1 = tanh_fast(d1v + fb_r1) * S.xd[16 + l16];
                        float t2 = v0 + v1;
                        t2 += __shfl_xor(t2, 1);
                        t2 += __shfl_xor(t2, 2);
                        t2 += __shfl_xor(t2, 4);
                        t2 += __shfl_xor(t2, 8);        // sum over 32 rows
                        float ksum = t2 + tanh_fast(dxv + fb_rx) * S.xd[32];
                        if (l16 == 0) {
                            float yg = S.y[g16];
                            if (st == 0)      { ka = ksum; S.yt[g16] = yg + 0.5f*hs*ksum; }
                            else if (st == 1) { kb = ksum; S.yt[g16] = yg + 0.5f*hs*ksum; }
                            else if (st == 2) { kc = ksum; S.yt[g16] = yg + hs*ksum; }
                            else S.y[g16] = yg + hs*(1.f/6.f)*(ka + 2.f*kb + 2.f*kc + ksum);
                        }
                    }
                } else {
                    // fallback: direct VALU output (correct, not fast)
                    float a0 = 0.f, a1 = 0.f, ax = 0.f;
                    #pragma unroll 2
                    for (int j = 0; j < 16; ++j) {
                        const float4* h4 = (const float4*)(hin + j*8);
                        float4 ha = h4[0], hb2 = h4[1];
                        float w8[8];
                        P::ld8(fWo, r0*WID + j*8, w8);
                        a0 += w8[0]*ha.x + w8[1]*ha.y + w8[2]*ha.z + w8[3]*ha.w
                            + w8[4]*hb2.x + w8[5]*hb2.y + w8[6]*hb2.z + w8[7]*hb2.w;
                        P::ld8(fWo, r1*WID + j*8, w8);
                        a1 += w8[0]*ha.x + w8[1]*ha.y + w8[2]*ha.z + w8[3]*ha.w
                            + w8[4]*hb2.x + w8[5]*hb2.y + w8[6]*hb2.z + w8[7]*hb2.w;
                    }
                    {
                        float w8[8];
                        P::ld8(fWo, rx*WID + l16*8, w8);
                        const float4* h4 = (const float4*)(hin + l16*8);
                        float4 ha = h4[0], hb2 = h4[1];
                        ax = w8[0]*ha.x + w8[1]*ha.y + w8[2]*ha.z + w8[3]*ha.w
                           + w8[4]*hb2.x + w8[5]*hb2.y + w8[6]*hb2.z + w8[7]*hb2.w;
                    }
                    ax += __shfl_xor(ax, 1);
                    ax += __shfl_xor(ax, 2);
                    ax += __shfl_xor(ax, 4);
                    ax += __shfl_xor(ax, 8);
                    float v0 = tanh_fast(a0 + fb_r0) * S.xd[l16];
                    float v1 = tanh_fast(a1 + fb_r1) * S.xd[16 + l16];
                    float t2 = v0 + v1;
                    t2 += __shfl_xor(t2, 1);
                    t2 += __shfl_xor(t2, 2);
                    t2 += __shfl_xor(t2, 4);
                    t2 += __shfl_xor(t2, 8);
                    float ksum = t2 + tanh_fast(ax + fb_rx) * S.xd[32];
                    if (l16 == 0) {
                        float yg = S.y[g16];
                        if (st == 0)      { ka = ksum; S.yt[g16] = yg + 0.5f*hs*ksum; }
                        else if (st == 1) { kb = ksum; S.yt[g16] = yg + 0.5f*hs*ksum; }
                        else if (st == 2) { kc = ksum; S.yt[g16] = yg + hs*ksum; }
                        else S.y[g16] = yg + hs*(1.f/6.f)*(ka + 2.f*kb + 2.f*kc + ksum);
                    }
                }
                __syncthreads();                                   // B6
            }
        }

        if (tid < OUTD) {
            float a = P::ld(lb, tid);
            #pragma unroll 8
            for (int k2 = 0; k2 < HID; ++k2) a += S.lWt[k2*OUTD + tid] * S.y[k2];
            P::st(out, b*T_N*OUTD + (iv+1)*OUTD + tid, a);
        }
    }
}

__global__ __launch_bounds__(NTH)
void cde_kernel(const void* ts, const void* ys, const void* iW0, const void* ib0,
                const void* iWh, const void* ibh, const void* iWo, const void* ibo,
                const void* fW0, const void* fb0, const void* fWh, const void* fbh,
                const void* fWo, const void* fbo, const void* lW, const void* lb,
                const unsigned short* ws, int use_ws, void* out)
{
    __shared__ Smem S;
    const bool isbf = (((const unsigned short*)ts)[1] == 0x3C00);
    if (use_ws) {
        if (isbf)
            run_cde<PolBF16, true>(ts, ys, iW0, ib0, iWh, ibh, iWo, ibo,
                                   fW0, fb0, fWh, fbh, fWo, fbo, lW, lb,
                                   ws, out, S);
        else
            run_cde<PolF32, true>(ts, ys, iW0, ib0, iWh, ibh, iWo, ibo,
                                  fW0, fb0, fWh, fbh, fWo, fbo, lW, lb,
                                  ws, out, S);
    } else {
        if (isbf)
            run_cde<PolBF16, false>(ts, ys, iW0, ib0, iWh, ibh, iWo, ibo,
                                    fW0, fb0, fWh, fbh, fWo, fbo, lW, lb,
                                    fWo, out, S);
        else
            run_cde<PolF32, false>(ts, ys, iW0, ib0, iWh, ibh, iWo, ibo,
                                   fW0, fb0, fWh, fbh, fWo, fbo, lW, lb,
                                   fWo, out, S);
    }
}

extern "C" void kernel_launch(void* const* d_in, const int* in_sizes, int n_in,
                              void* d_out, int out_size, void* d_ws, size_t ws_size,
                              hipStream_t stream) {
    (void)in_sizes; (void)n_in; (void)out_size;
    const int use_ws = (ws_size >= WS_NEED) ? 1 : 0;
    if (use_ws) {
        const int nprep = (NPLANES * 64) / NTH;   // 33 blocks
        hipLaunchKernelGGL(prep_kernel, dim3(nprep), dim3(NTH), 0, stream,
                           d_in[0], d_in[12], (unsigned short*)d_ws);
    }
    hipLaunchKernelGGL(cde_kernel, dim3(B_N), dim3(NTH), 0, stream,
                       d_in[0], d_in[1], d_in[2], d_in[3], d_in[4], d_in[5],
                       d_in[6], d_in[7], d_in[8], d_in[9], d_in[10], d_in[11],
                       d_in[12], d_in[13], d_in[14], d_in[15],
                       (const unsigned short*)d_ws, use_ws, d_out);
}